// Round 1
// baseline (977.247 us; speedup 1.0000x reference)
//
#include <hip/hip_runtime.h>

#define NN 16384
#define EE 8192
#define KIN 256
#define FOUT 128

typedef short short8 __attribute__((ext_vector_type(8)));
typedef short short4v __attribute__((ext_vector_type(4)));
typedef float f32x4 __attribute__((ext_vector_type(4)));
typedef __bf16 bf16x8 __attribute__((ext_vector_type(8)));

// fp32 -> bf16 bits, round-to-nearest-even
__device__ inline unsigned short f2bf(float f) {
    union { float f; unsigned u; } v; v.f = f;
    unsigned r = v.u + 0x7fffu + ((v.u >> 16) & 1u);
    return (unsigned short)(r >> 16);
}

__device__ inline f32x4 mfma_bf16(short8 a, short8 b, f32x4 c) {
    union { short8 s; bf16x8 h; } ua, ub;
    ua.s = a; ub.s = b;
    return __builtin_amdgcn_mfma_f32_16x16x32_bf16(ua.h, ub.h, c, 0, 0, 0);
}

// ---------------- K1: yT[f][n] = bf16( (x @ W)[n][f] ) ----------------
// grid 256 blocks x 256 thr; wave owns 16 n-rows, all 128 f. K=256 (no loop tiling).
__global__ __launch_bounds__(256) void k1_xw_yT(
    const float* __restrict__ x, const float* __restrict__ w,
    unsigned short* __restrict__ yT) {
    __shared__ union {
        unsigned short wT[FOUT * KIN];   // 64 KB, [f][k] XOR-swizzled (16B chunks)
        unsigned short cT[FOUT * 72];    // epilogue transpose buffer
    } sm;
    const int t  = threadIdx.x;
    const int l  = t & 63;
    const int wv = t >> 6;
    const int q4 = l >> 4;

    // stage W transposed + bf16 + swizzled
    {
        const int f  = t >> 1;
        const int kh = (t & 1) * 128;
        #pragma unroll 4
        for (int q = 0; q < 16; ++q) {
            short8 pk;
            #pragma unroll
            for (int j = 0; j < 8; ++j)
                pk[j] = (short)f2bf(w[(kh + q * 8 + j) * FOUT + f]);
            int c = ((kh >> 3) + q) ^ (f & 7);
            *(short8*)&sm.wT[f * KIN + c * 8] = pk;
        }
    }
    __syncthreads();

    const int nBase = blockIdx.x * 64;
    const int n = nBase + wv * 16 + (l & 15);
    f32x4 acc[8];
    #pragma unroll
    for (int i = 0; i < 8; ++i) acc[i] = (f32x4)0.0f;

    #pragma unroll
    for (int kk = 0; kk < 8; ++kk) {
        const float* xr = x + (size_t)n * KIN + kk * 32 + q4 * 8;
        float4 v0 = *(const float4*)xr;
        float4 v1 = *(const float4*)(xr + 4);
        short8 a;
        a[0] = (short)f2bf(v0.x); a[1] = (short)f2bf(v0.y);
        a[2] = (short)f2bf(v0.z); a[3] = (short)f2bf(v0.w);
        a[4] = (short)f2bf(v1.x); a[5] = (short)f2bf(v1.y);
        a[6] = (short)f2bf(v1.z); a[7] = (short)f2bf(v1.w);
        #pragma unroll
        for (int ft = 0; ft < 8; ++ft) {
            int f = ft * 16 + (l & 15);
            int c = (kk * 4 + q4) ^ (f & 7);
            short8 b = *(const short8*)&sm.wT[f * KIN + c * 8];
            acc[ft] = mfma_bf16(a, b, acc[ft]);
        }
    }
    __syncthreads();   // done with wT, reuse as cT

    #pragma unroll
    for (int ft = 0; ft < 8; ++ft) {
        short4v pk;
        #pragma unroll
        for (int r = 0; r < 4; ++r) pk[r] = (short)f2bf(acc[ft][r]);
        int f = ft * 16 + (l & 15);
        *(short4v*)&sm.cT[f * 72 + wv * 16 + q4 * 4] = pk;
    }
    __syncthreads();
    {
        const int f  = t >> 1;
        const int nh = (t & 1) * 32;
        #pragma unroll
        for (int qq = 0; qq < 4; ++qq) {
            short8 v = *(const short8*)&sm.cT[f * 72 + nh + qq * 8];
            *(short8*)&yT[(size_t)f * NN + nBase + nh + qq * 8] = v;
        }
    }
}

// ---------------- K2: eyf[e][f] += D_v[e] * (MT @ y)[e][f] ----------------
// grid (128, 4): block.x = 64-e tile, block.y = k-split over N. fp32 atomic out.
__global__ __launch_bounds__(256) void k2_mt_y(
    const float* __restrict__ MT, const unsigned short* __restrict__ yT,
    const float* __restrict__ dv, float* __restrict__ eyf) {
    __shared__ unsigned short blds[FOUT * 64];   // 16 KB, [f][k] swizzled
    const int t  = threadIdx.x;
    const int l  = t & 63;
    const int wv = t >> 6;
    const int q4 = l >> 4;
    const int eBase = blockIdx.x * 64;
    const int s = blockIdx.y;
    const int e = eBase + wv * 16 + (l & 15);
    const float sA = dv[e];
    const float* arow = MT + (size_t)e * NN;

    f32x4 acc[8];
    #pragma unroll
    for (int i = 0; i < 8; ++i) acc[i] = (f32x4)0.0f;

    const int sf = t >> 1;
    const int skoff = (t & 1) * 32;
    const int scb = skoff >> 3;
    const int sfx = sf & 7;

    for (int cc = 0; cc < 64; ++cc) {
        const int k0 = s * 4096 + cc * 64;
        {   // stage B chunk (yT) into LDS
            const unsigned short* src = yT + (size_t)sf * NN + k0 + skoff;
            short8 v0 = *(const short8*)(src);
            short8 v1 = *(const short8*)(src + 8);
            short8 v2 = *(const short8*)(src + 16);
            short8 v3 = *(const short8*)(src + 24);
            *(short8*)&blds[sf * 64 + ((scb + 0) ^ sfx) * 8] = v0;
            *(short8*)&blds[sf * 64 + ((scb + 1) ^ sfx) * 8] = v1;
            *(short8*)&blds[sf * 64 + ((scb + 2) ^ sfx) * 8] = v2;
            *(short8*)&blds[sf * 64 + ((scb + 3) ^ sfx) * 8] = v3;
        }
        __syncthreads();
        #pragma unroll
        for (int kk = 0; kk < 2; ++kk) {
            const float* ar = arow + k0 + kk * 32 + q4 * 8;
            float4 v0 = *(const float4*)ar;
            float4 v1 = *(const float4*)(ar + 4);
            short8 a;
            a[0] = (short)f2bf(sA * v0.x); a[1] = (short)f2bf(sA * v0.y);
            a[2] = (short)f2bf(sA * v0.z); a[3] = (short)f2bf(sA * v0.w);
            a[4] = (short)f2bf(sA * v1.x); a[5] = (short)f2bf(sA * v1.y);
            a[6] = (short)f2bf(sA * v1.z); a[7] = (short)f2bf(sA * v1.w);
            #pragma unroll
            for (int ft = 0; ft < 8; ++ft) {
                int f = ft * 16 + (l & 15);
                int c = (kk * 4 + q4) ^ (f & 7);
                short8 b = *(const short8*)&blds[f * 64 + c * 8];
                acc[ft] = mfma_bf16(a, b, acc[ft]);
            }
        }
        __syncthreads();
    }
    #pragma unroll
    for (int ft = 0; ft < 8; ++ft) {
        int f  = ft * 16 + (l & 15);
        int eo = eBase + wv * 16 + q4 * 4;
        #pragma unroll
        for (int r = 0; r < 4; ++r)
            atomicAdd(&eyf[(size_t)(eo + r) * FOUT + f], acc[ft][r]);
    }
}

// ---------------- K2b: eyT[f][e] = bf16(eyf[e][f]) ----------------
__global__ __launch_bounds__(256) void k2b_cvtT(
    const float* __restrict__ eyf, unsigned short* __restrict__ eyT) {
    int idx = blockIdx.x * 256 + threadIdx.x;   // 128 * 1024
    int e8 = idx & 1023;
    int f  = idx >> 10;
    short8 pk;
    #pragma unroll
    for (int j = 0; j < 8; ++j)
        pk[j] = (short)f2bf(eyf[(size_t)(e8 * 8 + j) * FOUT + f]);
    *(short8*)&eyT[(size_t)f * EE + e8 * 8] = pk;
}

// ---------------- K3: out[n][f] += 0.5*D_e[n] * (MT^T @ ey)[n][f] ----------------
// grid (256, 2): block.x = 64-n tile, block.y = k-split over E.
// A-frags gathered per-lane from MT columns: 16 consecutive-n lanes -> 64B segments.
__global__ __launch_bounds__(256) void k3_mtT_ey(
    const float* __restrict__ MT, const unsigned short* __restrict__ eyT,
    const float* __restrict__ de, float* __restrict__ out) {
    __shared__ unsigned short blds[FOUT * 64];
    const int t  = threadIdx.x;
    const int l  = t & 63;
    const int wv = t >> 6;
    const int q4 = l >> 4;
    const int nBase = blockIdx.x * 64;
    const int s = blockIdx.y;
    const int n = nBase + wv * 16 + (l & 15);
    const float sA = 0.5f * de[n];

    f32x4 acc[8];
    #pragma unroll
    for (int i = 0; i < 8; ++i) acc[i] = (f32x4)0.0f;

    const int sf = t >> 1;
    const int skoff = (t & 1) * 32;
    const int scb = skoff >> 3;
    const int sfx = sf & 7;

    for (int cc = 0; cc < 64; ++cc) {
        const int k0 = s * 4096 + cc * 64;
        {   // stage B chunk (eyT) into LDS
            const unsigned short* src = eyT + (size_t)sf * EE + k0 + skoff;
            short8 v0 = *(const short8*)(src);
            short8 v1 = *(const short8*)(src + 8);
            short8 v2 = *(const short8*)(src + 16);
            short8 v3 = *(const short8*)(src + 24);
            *(short8*)&blds[sf * 64 + ((scb + 0) ^ sfx) * 8] = v0;
            *(short8*)&blds[sf * 64 + ((scb + 1) ^ sfx) * 8] = v1;
            *(short8*)&blds[sf * 64 + ((scb + 2) ^ sfx) * 8] = v2;
            *(short8*)&blds[sf * 64 + ((scb + 3) ^ sfx) * 8] = v3;
        }
        __syncthreads();
        #pragma unroll
        for (int kk = 0; kk < 2; ++kk) {
            // A[m=n][k=e] = sA * MT[e][n]; 8-dword column gather
            const float* ap = MT + (size_t)(k0 + kk * 32 + q4 * 8) * NN + n;
            float av[8];
            #pragma unroll
            for (int j = 0; j < 8; ++j) av[j] = ap[(size_t)j * NN];
            short8 a;
            #pragma unroll
            for (int j = 0; j < 8; ++j) a[j] = (short)f2bf(sA * av[j]);
            #pragma unroll
            for (int ft = 0; ft < 8; ++ft) {
                int f = ft * 16 + (l & 15);
                int c = (kk * 4 + q4) ^ (f & 7);
                short8 b = *(const short8*)&blds[f * 64 + c * 8];
                acc[ft] = mfma_bf16(a, b, acc[ft]);
            }
        }
        __syncthreads();
    }
    #pragma unroll
    for (int ft = 0; ft < 8; ++ft) {
        int f  = ft * 16 + (l & 15);
        int no = nBase + wv * 16 + q4 * 4;
        #pragma unroll
        for (int r = 0; r < 4; ++r)
            atomicAdd(&out[(size_t)(no + r) * FOUT + f], acc[ft][r]);
    }
}

extern "C" void kernel_launch(void* const* d_in, const int* in_sizes, int n_in,
                              void* d_out, int out_size, void* d_ws, size_t ws_size,
                              hipStream_t stream) {
    const float* x  = (const float*)d_in[0];
    const float* w  = (const float*)d_in[1];
    const float* MT = (const float*)d_in[2];
    const float* dv = (const float*)d_in[3];
    const float* de = (const float*)d_in[4];
    float* out = (float*)d_out;

    char* ws = (char*)d_ws;
    unsigned short* yT  = (unsigned short*)(ws);                 // [128][16384] bf16, 4 MB
    unsigned short* eyT = (unsigned short*)(ws + (4u << 20));    // [128][8192]  bf16, 2 MB
    float*          eyf = (float*)(ws + (6u << 20));             // [8192][128]  f32,  4 MB

    hipMemsetAsync(out, 0, (size_t)NN * FOUT * sizeof(float), stream);
    hipMemsetAsync(eyf, 0, (size_t)EE * FOUT * sizeof(float), stream);

    k1_xw_yT <<<256, 256, 0, stream>>>(x, w, yT);
    k2_mt_y  <<<dim3(128, 4), 256, 0, stream>>>(MT, yT, dv, eyf);
    k2b_cvtT <<<512, 256, 0, stream>>>(eyf, eyT);
    k3_mtT_ey<<<dim3(256, 2), 256, 0, stream>>>(MT, eyT, de, out);
}

// Round 2
// 906.617 us; speedup vs baseline: 1.0779x; 1.0779x over previous
//
#include <hip/hip_runtime.h>

#define NN 16384
#define EE 8192
#define KIN 256
#define FOUT 128

typedef short short8 __attribute__((ext_vector_type(8)));
typedef short short4v __attribute__((ext_vector_type(4)));
typedef float f32x4 __attribute__((ext_vector_type(4)));
typedef __bf16 bf16x8 __attribute__((ext_vector_type(8)));

// fp32 -> bf16 bits, round-to-nearest-even
__device__ inline unsigned short f2bf(float f) {
    union { float f; unsigned u; } v; v.f = f;
    unsigned r = v.u + 0x7fffu + ((v.u >> 16) & 1u);
    return (unsigned short)(r >> 16);
}

__device__ inline f32x4 mfma_bf16(short8 a, short8 b, f32x4 c) {
    union { short8 s; bf16x8 h; } ua, ub;
    ua.s = a; ub.s = b;
    return __builtin_amdgcn_mfma_f32_16x16x32_bf16(ua.h, ub.h, c, 0, 0, 0);
}

// ---------------- K1: yT[f][n] = bf16( (x @ W)[n][f] ) ----------------
__global__ __launch_bounds__(256) void k1_xw_yT(
    const float* __restrict__ x, const float* __restrict__ w,
    unsigned short* __restrict__ yT) {
    __shared__ union {
        unsigned short wT[FOUT * KIN];   // 64 KB, [f][k] XOR-swizzled (16B chunks)
        unsigned short cT[FOUT * 72];    // epilogue transpose buffer
    } sm;
    const int t  = threadIdx.x;
    const int l  = t & 63;
    const int wv = t >> 6;
    const int q4 = l >> 4;

    {   // stage W transposed + bf16 + swizzled
        const int f  = t >> 1;
        const int kh = (t & 1) * 128;
        #pragma unroll 4
        for (int q = 0; q < 16; ++q) {
            short8 pk;
            #pragma unroll
            for (int j = 0; j < 8; ++j)
                pk[j] = (short)f2bf(w[(kh + q * 8 + j) * FOUT + f]);
            int c = ((kh >> 3) + q) ^ (f & 7);
            *(short8*)&sm.wT[f * KIN + c * 8] = pk;
        }
    }
    __syncthreads();

    const int nBase = blockIdx.x * 64;
    const int n = nBase + wv * 16 + (l & 15);
    f32x4 acc[8];
    #pragma unroll
    for (int i = 0; i < 8; ++i) acc[i] = (f32x4)0.0f;

    #pragma unroll
    for (int kk = 0; kk < 8; ++kk) {
        const float* xr = x + (size_t)n * KIN + kk * 32 + q4 * 8;
        float4 v0 = *(const float4*)xr;
        float4 v1 = *(const float4*)(xr + 4);
        short8 a;
        a[0] = (short)f2bf(v0.x); a[1] = (short)f2bf(v0.y);
        a[2] = (short)f2bf(v0.z); a[3] = (short)f2bf(v0.w);
        a[4] = (short)f2bf(v1.x); a[5] = (short)f2bf(v1.y);
        a[6] = (short)f2bf(v1.z); a[7] = (short)f2bf(v1.w);
        #pragma unroll
        for (int ft = 0; ft < 8; ++ft) {
            int f = ft * 16 + (l & 15);
            int c = (kk * 4 + q4) ^ (f & 7);
            short8 b = *(const short8*)&sm.wT[f * KIN + c * 8];
            acc[ft] = mfma_bf16(a, b, acc[ft]);
        }
    }
    __syncthreads();

    #pragma unroll
    for (int ft = 0; ft < 8; ++ft) {
        short4v pk;
        #pragma unroll
        for (int r = 0; r < 4; ++r) pk[r] = (short)f2bf(acc[ft][r]);
        int f = ft * 16 + (l & 15);
        *(short4v*)&sm.cT[f * 72 + wv * 16 + q4 * 4] = pk;
    }
    __syncthreads();
    {
        const int f  = t >> 1;
        const int nh = (t & 1) * 32;
        #pragma unroll
        for (int qq = 0; qq < 4; ++qq) {
            short8 v = *(const short8*)&sm.cT[f * 72 + nh + qq * 8];
            *(short8*)&yT[(size_t)f * NN + nBase + nh + qq * 8] = v;
        }
    }
}

// ---------------- K2: eyf[e][f] += D_v[e] * (MT @ y)[e][f] ----------------
// grid (128, 8): 4 blocks/CU, double-buffered LDS, 1 barrier/chunk.
__global__ __launch_bounds__(256, 4) void k2_mt_y(
    const float* __restrict__ MT, const unsigned short* __restrict__ yT,
    const float* __restrict__ dv, float* __restrict__ eyf) {
    __shared__ unsigned short blds[2][FOUT * 64];   // 2 x 16 KB, [f][k] swizzled
    const int t  = threadIdx.x;
    const int l  = t & 63;
    const int wv = t >> 6;
    const int q4 = l >> 4;
    const int eBase = blockIdx.x * 64;
    const int sBase = blockIdx.y * 2048;
    const int e = eBase + wv * 16 + (l & 15);
    const float sA = dv[e];
    const float* arow = MT + (size_t)e * NN;

    f32x4 acc[8];
    #pragma unroll
    for (int i = 0; i < 8; ++i) acc[i] = (f32x4)0.0f;

    const int sf = t >> 1;
    const int skoff = (t & 1) * 32;
    const int scb = skoff >> 3;
    const int sfx = sf & 7;
    const unsigned short* srcBase = yT + (size_t)sf * NN + skoff;

    {   // prologue: stage chunk 0 into buf 0
        const unsigned short* src = srcBase + sBase;
        short8 v0 = *(const short8*)(src);
        short8 v1 = *(const short8*)(src + 8);
        short8 v2 = *(const short8*)(src + 16);
        short8 v3 = *(const short8*)(src + 24);
        *(short8*)&blds[0][sf * 64 + ((scb + 0) ^ sfx) * 8] = v0;
        *(short8*)&blds[0][sf * 64 + ((scb + 1) ^ sfx) * 8] = v1;
        *(short8*)&blds[0][sf * 64 + ((scb + 2) ^ sfx) * 8] = v2;
        *(short8*)&blds[0][sf * 64 + ((scb + 3) ^ sfx) * 8] = v3;
    }

    for (int cc = 0; cc < 32; ++cc) {
        const int k0 = sBase + cc * 64;
        __syncthreads();   // buf[cc&1] staged; prior reads of buf[(cc+1)&1] done

        // A loads for this chunk (issue first so MFMA waits only on these)
        float4 a0[2], a1[2];
        #pragma unroll
        for (int kk = 0; kk < 2; ++kk) {
            const float* ar = arow + k0 + kk * 32 + q4 * 8;
            a0[kk] = *(const float4*)ar;
            a1[kk] = *(const float4*)(ar + 4);
        }
        // B staging loads for next chunk (stay in flight during compute)
        short8 v0, v1, v2, v3;
        if (cc != 31) {
            const unsigned short* src = srcBase + k0 + 64;
            v0 = *(const short8*)(src);
            v1 = *(const short8*)(src + 8);
            v2 = *(const short8*)(src + 16);
            v3 = *(const short8*)(src + 24);
        }
        // compute from buf[cc&1]
        #pragma unroll
        for (int kk = 0; kk < 2; ++kk) {
            short8 a;
            a[0] = (short)f2bf(sA * a0[kk].x); a[1] = (short)f2bf(sA * a0[kk].y);
            a[2] = (short)f2bf(sA * a0[kk].z); a[3] = (short)f2bf(sA * a0[kk].w);
            a[4] = (short)f2bf(sA * a1[kk].x); a[5] = (short)f2bf(sA * a1[kk].y);
            a[6] = (short)f2bf(sA * a1[kk].z); a[7] = (short)f2bf(sA * a1[kk].w);
            #pragma unroll
            for (int ft = 0; ft < 8; ++ft) {
                int f = ft * 16 + (l & 15);
                int c = (kk * 4 + q4) ^ (f & 7);
                short8 b = *(const short8*)&blds[cc & 1][f * 64 + c * 8];
                acc[ft] = mfma_bf16(a, b, acc[ft]);
            }
        }
        // commit staged chunk into the other buffer
        if (cc != 31) {
            unsigned short* dst = &blds[(cc + 1) & 1][sf * 64];
            *(short8*)&dst[((scb + 0) ^ sfx) * 8] = v0;
            *(short8*)&dst[((scb + 1) ^ sfx) * 8] = v1;
            *(short8*)&dst[((scb + 2) ^ sfx) * 8] = v2;
            *(short8*)&dst[((scb + 3) ^ sfx) * 8] = v3;
        }
    }
    #pragma unroll
    for (int ft = 0; ft < 8; ++ft) {
        int f  = ft * 16 + (l & 15);
        int eo = eBase + wv * 16 + q4 * 4;
        #pragma unroll
        for (int r = 0; r < 4; ++r)
            atomicAdd(&eyf[(size_t)(eo + r) * FOUT + f], acc[ft][r]);
    }
}

// ---------------- K2b: eyT[f][e] = bf16(eyf[e][f]) ----------------
__global__ __launch_bounds__(256) void k2b_cvtT(
    const float* __restrict__ eyf, unsigned short* __restrict__ eyT) {
    int idx = blockIdx.x * 256 + threadIdx.x;   // 128 * 1024
    int e8 = idx & 1023;
    int f  = idx >> 10;
    short8 pk;
    #pragma unroll
    for (int j = 0; j < 8; ++j)
        pk[j] = (short)f2bf(eyf[(size_t)(e8 * 8 + j) * FOUT + f]);
    *(short8*)&eyT[(size_t)f * EE + e8 * 8] = pk;
}

// ---------------- K3: out[n][f] += 0.5*D_e[n] * (MT^T @ ey)[n][f] ----------------
// grid (256, 4): 4 blocks/CU, double-buffered LDS, 1 barrier/chunk.
__global__ __launch_bounds__(256, 4) void k3_mtT_ey(
    const float* __restrict__ MT, const unsigned short* __restrict__ eyT,
    const float* __restrict__ de, float* __restrict__ out) {
    __shared__ unsigned short blds[2][FOUT * 64];
    const int t  = threadIdx.x;
    const int l  = t & 63;
    const int wv = t >> 6;
    const int q4 = l >> 4;
    const int nBase = blockIdx.x * 64;
    const int sBase = blockIdx.y * 2048;
    const int n = nBase + wv * 16 + (l & 15);
    const float sA = 0.5f * de[n];

    f32x4 acc[8];
    #pragma unroll
    for (int i = 0; i < 8; ++i) acc[i] = (f32x4)0.0f;

    const int sf = t >> 1;
    const int skoff = (t & 1) * 32;
    const int scb = skoff >> 3;
    const int sfx = sf & 7;
    const unsigned short* srcBase = eyT + (size_t)sf * EE + skoff;

    {   // prologue: stage chunk 0 into buf 0
        const unsigned short* src = srcBase + sBase;
        short8 v0 = *(const short8*)(src);
        short8 v1 = *(const short8*)(src + 8);
        short8 v2 = *(const short8*)(src + 16);
        short8 v3 = *(const short8*)(src + 24);
        *(short8*)&blds[0][sf * 64 + ((scb + 0) ^ sfx) * 8] = v0;
        *(short8*)&blds[0][sf * 64 + ((scb + 1) ^ sfx) * 8] = v1;
        *(short8*)&blds[0][sf * 64 + ((scb + 2) ^ sfx) * 8] = v2;
        *(short8*)&blds[0][sf * 64 + ((scb + 3) ^ sfx) * 8] = v3;
    }

    for (int cc = 0; cc < 32; ++cc) {
        const int k0 = sBase + cc * 64;
        __syncthreads();

        // A column-gather loads: 16 consecutive-n lanes form 64 B segments
        float av[2][8];
        #pragma unroll
        for (int kk = 0; kk < 2; ++kk) {
            const float* ap = MT + (size_t)(k0 + kk * 32 + q4 * 8) * NN + n;
            #pragma unroll
            for (int j = 0; j < 8; ++j) av[kk][j] = ap[(size_t)j * NN];
        }
        // B staging loads for next chunk
        short8 v0, v1, v2, v3;
        if (cc != 31) {
            const unsigned short* src = srcBase + k0 + 64;
            v0 = *(const short8*)(src);
            v1 = *(const short8*)(src + 8);
            v2 = *(const short8*)(src + 16);
            v3 = *(const short8*)(src + 24);
        }
        #pragma unroll
        for (int kk = 0; kk < 2; ++kk) {
            short8 a;
            #pragma unroll
            for (int j = 0; j < 8; ++j) a[j] = (short)f2bf(sA * av[kk][j]);
            #pragma unroll
            for (int ft = 0; ft < 8; ++ft) {
                int f = ft * 16 + (l & 15);
                int c = (kk * 4 + q4) ^ (f & 7);
                short8 b = *(const short8*)&blds[cc & 1][f * 64 + c * 8];
                acc[ft] = mfma_bf16(a, b, acc[ft]);
            }
        }
        if (cc != 31) {
            unsigned short* dst = &blds[(cc + 1) & 1][sf * 64];
            *(short8*)&dst[((scb + 0) ^ sfx) * 8] = v0;
            *(short8*)&dst[((scb + 1) ^ sfx) * 8] = v1;
            *(short8*)&dst[((scb + 2) ^ sfx) * 8] = v2;
            *(short8*)&dst[((scb + 3) ^ sfx) * 8] = v3;
        }
    }
    #pragma unroll
    for (int ft = 0; ft < 8; ++ft) {
        int f  = ft * 16 + (l & 15);
        int no = nBase + wv * 16 + q4 * 4;
        #pragma unroll
        for (int r = 0; r < 4; ++r)
            atomicAdd(&out[(size_t)(no + r) * FOUT + f], acc[ft][r]);
    }
}

extern "C" void kernel_launch(void* const* d_in, const int* in_sizes, int n_in,
                              void* d_out, int out_size, void* d_ws, size_t ws_size,
                              hipStream_t stream) {
    const float* x  = (const float*)d_in[0];
    const float* w  = (const float*)d_in[1];
    const float* MT = (const float*)d_in[2];
    const float* dv = (const float*)d_in[3];
    const float* de = (const float*)d_in[4];
    float* out = (float*)d_out;

    char* ws = (char*)d_ws;
    unsigned short* yT  = (unsigned short*)(ws);                 // [128][16384] bf16, 4 MB
    unsigned short* eyT = (unsigned short*)(ws + (4u << 20));    // [128][8192]  bf16, 2 MB
    float*          eyf = (float*)(ws + (6u << 20));             // [8192][128]  f32,  4 MB

    hipMemsetAsync(out, 0, (size_t)NN * FOUT * sizeof(float), stream);
    hipMemsetAsync(eyf, 0, (size_t)EE * FOUT * sizeof(float), stream);

    k1_xw_yT <<<256, 256, 0, stream>>>(x, w, yT);
    k2_mt_y  <<<dim3(128, 8), 256, 0, stream>>>(MT, yT, dv, eyf);
    k2b_cvtT <<<512, 256, 0, stream>>>(eyf, eyT);
    k3_mtT_ey<<<dim3(256, 4), 256, 0, stream>>>(MT, eyT, de, out);
}